// Round 7
// baseline (329.446 us; speedup 1.0000x reference)
//
#include <hip/hip_runtime.h>
#include <hip/hip_fp16.h>

#define N_USERS 40000
#define N_ITEMS 20000
#define N_TOTAL (N_USERS + N_ITEMS)
#define D 64
#define N_GRP 8
#define ITEMS_PER_GRP (N_ITEMS / N_GRP)   // 2500, exact

union H8 { uint4 u; __half h[8]; };

// ---------------- CSR construction ----------------

__global__ void rowptr_u_kernel(const int* __restrict__ u_idx, int* __restrict__ pu, int nnz) {
    int u = blockIdx.x * blockDim.x + threadIdx.x;
    if (u > N_USERS) return;
    int lo = 0, hi = nnz;
    while (lo < hi) { int mid = (lo + hi) >> 1; if (u_idx[mid] < u) lo = mid + 1; else hi = mid; }
    pu[u] = lo;
}

__global__ void count_i_kernel(const int* __restrict__ i_idx, int* __restrict__ cnt, int nnz) {
    int e = blockIdx.x * blockDim.x + threadIdx.x;
    if (e >= nnz) return;
    atomicAdd(cnt + __builtin_nontemporal_load(i_idx + e), 1);
}

__global__ void scan_i_kernel(const int* __restrict__ cnt, int* __restrict__ rptr, int n) {
    __shared__ int partial[1024];
    int t = threadIdx.x;
    const int CH = (n + 1023) / 1024;
    int start = t * CH, end = min(start + CH, n);
    int s = 0;
    for (int k = start; k < end; ++k) s += cnt[k];
    partial[t] = s;
    __syncthreads();
    for (int off = 1; off < 1024; off <<= 1) {
        int v = (t >= off) ? partial[t - off] : 0;
        __syncthreads();
        partial[t] += v;
        __syncthreads();
    }
    int run = (t == 0) ? 0 : partial[t - 1];
    for (int k = start; k < end; ++k) { rptr[k] = run; run += cnt[k]; }
    if (t == 1023) rptr[n] = partial[1023];
}

// XCD-affine partitioned fill: blocks with blockIdx%8==g claim only edges whose
// item is in range [g*2500,(g+1)*2500). With round-robin block->XCD dispatch each
// destination slice (~1MB) is written by ONE XCD's L2 -> lines fill and write
// back once (kills the 8x cross-XCD writeback amplification seen as 61MB).
// Correctness does not depend on the dispatch mapping, only perf.
__global__ void fill_pairs_kernel(const int* __restrict__ i_idx, const int* __restrict__ u_idx,
                                  const int* __restrict__ pi, int* __restrict__ fill,
                                  int2* __restrict__ pairs, int nnz) {
    int grp = blockIdx.x & (N_GRP - 1);
    int sub = blockIdx.x >> 3;
    int nsub = gridDim.x >> 3;
    int lo = grp * ITEMS_PER_GRP, hi = lo + ITEMS_PER_GRP;
    int stride = nsub * blockDim.x;
    for (int e = sub * blockDim.x + threadIdx.x; e < nnz; e += stride) {
        int i = __builtin_nontemporal_load(i_idx + e);
        if (i >= lo && i < hi) {
            int u = __builtin_nontemporal_load(u_idx + e);
            int pos = atomicAdd(fill + i, 1);
            pairs[pi[i] + pos] = make_int2(e, u);
        }
    }
}

// fused w2-gather + item diag: wave per item
__global__ void diagw_kernel(const float* __restrict__ sims, const int2* __restrict__ pairs,
                             const int* __restrict__ pi, float* __restrict__ w2,
                             float* __restrict__ diag) {
    int i = (blockIdx.x * blockDim.x + threadIdx.x) >> 6;
    int lane = threadIdx.x & 63;
    if (i >= N_ITEMS) return;
    int b = pi[i], e = pi[i + 1];
    float s = 0.f;
    for (int k = b + lane; k < e; k += 64) {
        float w = sims[pairs[k].x];
        w2[k] = w;
        s += w;
    }
    #pragma unroll
    for (int m = 1; m < 64; m <<= 1) s += __shfl_xor(s, m, 64);
    if (lane == 0) diag[N_USERS + i] = s;
}

// fp32 -> fp16, 8 elements per thread
__global__ void tohalf_kernel(const float* __restrict__ src, __half* __restrict__ dst, int n8) {
    int t = blockIdx.x * blockDim.x + threadIdx.x;
    if (t >= n8) return;
    const float4* s = (const float4*)(src + (size_t)t * 8);
    float4 a = s[0], b = s[1];
    H8 o;
    o.h[0] = __float2half(a.x); o.h[1] = __float2half(a.y);
    o.h[2] = __float2half(a.z); o.h[3] = __float2half(a.w);
    o.h[4] = __float2half(b.x); o.h[5] = __float2half(b.y);
    o.h[6] = __float2half(b.z); o.h[7] = __float2half(b.w);
    ((uint4*)dst)[t] = o.u;
}

// ---------------- embeddings (fused: emb + acc init + invnorm; fp16 gather) ----------------
// wave per row; 8 edge-groups x 8 lanes x 8 halves; 2-way unrolled
// cs = column stride in ints (1 for i_idx, 2 for pairs.y)
__global__ void emb_kernel(const __half* __restrict__ ulH, const __half* __restrict__ ilH,
                           const int* __restrict__ i_idx, const int2* __restrict__ pairs,
                           const int* __restrict__ pu, const int* __restrict__ pi,
                           __half* __restrict__ embH, float* __restrict__ acc,
                           float* __restrict__ invn) {
    int wid = (blockIdx.x * blockDim.x + threadIdx.x) >> 6;
    int lane = threadIdx.x & 63;
    if (wid >= N_TOTAL) return;
    int g = lane >> 3, c = lane & 7;
    float s[8];
    #pragma unroll
    for (int j = 0; j < 8; ++j) s[j] = 0.f;
    const __half* tbl; const int* cols; int cs, b, e;
    if (wid < N_USERS) { tbl = ulH; cols = i_idx; cs = 1; b = pu[wid]; e = pu[wid + 1]; }
    else { int i = wid - N_USERS; tbl = ilH; cols = &pairs[0].y; cs = 2; b = pi[i]; e = pi[i + 1]; }
    int k = b + g;
    for (; k + 8 < e; k += 16) {
        H8 r0, r1;
        r0.u = ((const uint4*)(tbl + (size_t)cols[(size_t)k * cs] * D))[c];
        r1.u = ((const uint4*)(tbl + (size_t)cols[(size_t)(k + 8) * cs] * D))[c];
        #pragma unroll
        for (int j = 0; j < 8; ++j) s[j] += __half2float(r0.h[j]) + __half2float(r1.h[j]);
    }
    if (k < e) {
        H8 r0;
        r0.u = ((const uint4*)(tbl + (size_t)cols[(size_t)k * cs] * D))[c];
        #pragma unroll
        for (int j = 0; j < 8; ++j) s[j] += __half2float(r0.h[j]);
    }
    #pragma unroll
    for (int m = 8; m < 64; m <<= 1) {
        #pragma unroll
        for (int j = 0; j < 8; ++j) s[j] += __shfl_xor(s[j], m, 64);
    }
    float nsq = 0.f;
    #pragma unroll
    for (int j = 0; j < 8; ++j) nsq += s[j] * s[j];
    #pragma unroll
    for (int m = 1; m < 8; m <<= 1) nsq += __shfl_xor(nsq, m, 64);
    if (g == 0) {
        H8 o;
        #pragma unroll
        for (int j = 0; j < 8; ++j) o.h[j] = __float2half(s[j]);
        ((uint4*)(embH + (size_t)wid * D))[c] = o.u;
        float4* ap = (float4*)(acc + (size_t)wid * D);
        ap[c * 2]     = make_float4(s[0], s[1], s[2], s[3]);
        ap[c * 2 + 1] = make_float4(s[4], s[5], s[6], s[7]);
        if (c == 0) invn[wid] = 1.f / fmaxf(sqrtf(nsq), 1e-8f);
    }
}

// ---------------- sims (wave per user; fused user diag; fp16 gather; no atomics) ----------------
__global__ void sims_kernel(const __half* __restrict__ embH, const float* __restrict__ invn,
                            const int* __restrict__ i_idx, const int* __restrict__ pu,
                            float* __restrict__ sims, float* __restrict__ diag) {
    int u = (blockIdx.x * blockDim.x + threadIdx.x) >> 6;
    int lane = threadIdx.x & 63;
    if (u >= N_USERS) return;
    int g = lane >> 3, c = lane & 7;
    float invu = invn[u];
    H8 ur; ur.u = ((const uint4*)(embH + (size_t)u * D))[c];
    float un[8];
    #pragma unroll
    for (int j = 0; j < 8; ++j) un[j] = __half2float(ur.h[j]) * invu;
    int b = pu[u], e = pu[u + 1];
    float dsum = 0.f;
    int k = b + g;
    for (; k + 8 < e; k += 16) {
        int i0 = i_idx[k], i1 = i_idx[k + 8];
        H8 r0, r1;
        r0.u = ((const uint4*)(embH + (size_t)(N_USERS + i0) * D))[c];
        r1.u = ((const uint4*)(embH + (size_t)(N_USERS + i1) * D))[c];
        float d0 = 0.f, d1 = 0.f;
        #pragma unroll
        for (int j = 0; j < 8; ++j) {
            d0 += un[j] * __half2float(r0.h[j]);
            d1 += un[j] * __half2float(r1.h[j]);
        }
        #pragma unroll
        for (int m = 1; m < 8; m <<= 1) { d0 += __shfl_xor(d0, m, 64); d1 += __shfl_xor(d1, m, 64); }
        if (c == 0) {
            float sv0 = (d0 * invn[N_USERS + i0] + 1.f) * 0.5f;
            float sv1 = (d1 * invn[N_USERS + i1] + 1.f) * 0.5f;
            sims[k] = sv0; sims[k + 8] = sv1;
            dsum += sv0 + sv1;
        }
    }
    if (k < e) {
        int i0 = i_idx[k];
        H8 r0;
        r0.u = ((const uint4*)(embH + (size_t)(N_USERS + i0) * D))[c];
        float d0 = 0.f;
        #pragma unroll
        for (int j = 0; j < 8; ++j) d0 += un[j] * __half2float(r0.h[j]);
        #pragma unroll
        for (int m = 1; m < 8; m <<= 1) d0 += __shfl_xor(d0, m, 64);
        if (c == 0) {
            float sv0 = (d0 * invn[N_USERS + i0] + 1.f) * 0.5f;
            sims[k] = sv0;
            dsum += sv0;
        }
    }
    #pragma unroll
    for (int m = 8; m < 64; m <<= 1) dsum += __shfl_xor(dsum, m, 64);
    if (lane == 0) diag[u] = dsum;
}

// ---------------- propagation (fp16 gather, fp32 accumulate) ----------------
template <bool FINAL>
__global__ void prop_kernel(const __half* __restrict__ curH, __half* __restrict__ nextH,
                            float* __restrict__ acc, const float* __restrict__ sims,
                            const float* __restrict__ w2, const float* __restrict__ diag,
                            const int* __restrict__ i_idx, const int2* __restrict__ pairs,
                            const int* __restrict__ pu, const int* __restrict__ pi) {
    int wid = (blockIdx.x * blockDim.x + threadIdx.x) >> 6;
    int lane = threadIdx.x & 63;
    if (wid >= N_TOTAL) return;
    int g = lane >> 3, c = lane & 7;
    float s[8];
    #pragma unroll
    for (int j = 0; j < 8; ++j) s[j] = 0.f;
    const int* cols; const float* ws; int cs, b, e, colOff;
    if (wid < N_USERS) { b = pu[wid]; e = pu[wid + 1]; cols = i_idx; cs = 1; ws = sims; colOff = N_USERS; }
    else { int i = wid - N_USERS; b = pi[i]; e = pi[i + 1]; cols = &pairs[0].y; cs = 2; ws = w2; colOff = 0; }
    int k = b + g;
    for (; k + 8 < e; k += 16) {
        float w0 = ws[k], w1 = ws[k + 8];
        H8 r0, r1;
        r0.u = ((const uint4*)(curH + (size_t)(cols[(size_t)k * cs] + colOff) * D))[c];
        r1.u = ((const uint4*)(curH + (size_t)(cols[(size_t)(k + 8) * cs] + colOff) * D))[c];
        #pragma unroll
        for (int j = 0; j < 8; ++j) s[j] += w0 * __half2float(r0.h[j]) + w1 * __half2float(r1.h[j]);
    }
    if (k < e) {
        float w0 = ws[k];
        H8 r0;
        r0.u = ((const uint4*)(curH + (size_t)(cols[(size_t)k * cs] + colOff) * D))[c];
        #pragma unroll
        for (int j = 0; j < 8; ++j) s[j] += w0 * __half2float(r0.h[j]);
    }
    #pragma unroll
    for (int m = 8; m < 64; m <<= 1) {
        #pragma unroll
        for (int j = 0; j < 8; ++j) s[j] += __shfl_xor(s[j], m, 64);
    }
    if (g == 0) {
        float invd = 1.f / (diag[wid] + 1e-7f);
        float v[8];
        #pragma unroll
        for (int j = 0; j < 8; ++j) v[j] = s[j] * invd;
        float4* ap = (float4*)(acc + (size_t)wid * D);
        float4 a0 = ap[c * 2], a1 = ap[c * 2 + 1];
        if (FINAL) {
            a0.x = (a0.x + v[0]) * 0.25f; a0.y = (a0.y + v[1]) * 0.25f;
            a0.z = (a0.z + v[2]) * 0.25f; a0.w = (a0.w + v[3]) * 0.25f;
            a1.x = (a1.x + v[4]) * 0.25f; a1.y = (a1.y + v[5]) * 0.25f;
            a1.z = (a1.z + v[6]) * 0.25f; a1.w = (a1.w + v[7]) * 0.25f;
        } else {
            H8 o;
            #pragma unroll
            for (int j = 0; j < 8; ++j) o.h[j] = __float2half(v[j]);
            ((uint4*)(nextH + (size_t)wid * D))[c] = o.u;
            a0.x += v[0]; a0.y += v[1]; a0.z += v[2]; a0.w += v[3];
            a1.x += v[4]; a1.y += v[5]; a1.z += v[6]; a1.w += v[7];
        }
        ap[c * 2] = a0; ap[c * 2 + 1] = a1;
    }
}

// ---------------- launch ----------------

extern "C" void kernel_launch(void* const* d_in, const int* in_sizes, int n_in,
                              void* d_out, int out_size, void* d_ws, size_t ws_size,
                              hipStream_t stream) {
    const float* user_linear = (const float*)d_in[0];
    const float* item_linear = (const float*)d_in[1];
    const int* u_idx = (const int*)d_in[2];
    const int* i_idx = (const int*)d_in[3];
    const int nnz = in_sizes[2];

    // carve workspace (256B aligned)
    char* p = (char*)d_ws;
    auto carve = [&](size_t bytes) { void* r = (void*)p; p += (bytes + 255) & ~(size_t)255; return r; };
    __half* embA = (__half*)carve((size_t)N_TOTAL * D * 2);
    __half* embB = (__half*)carve((size_t)N_TOTAL * D * 2);
    __half* ulH  = (__half*)carve((size_t)N_ITEMS * D * 2);
    __half* ilH  = (__half*)carve((size_t)N_USERS * D * 2);
    float* sims = (float*)carve((size_t)nnz * 4);
    float* w2   = (float*)carve((size_t)nnz * 4);
    float* diag = (float*)carve((size_t)N_TOTAL * 4);
    float* invn = (float*)carve((size_t)N_TOTAL * 4);
    int* pu   = (int*)carve((size_t)(N_USERS + 1) * 4);
    int* pi   = (int*)carve((size_t)(N_ITEMS + 1) * 4);
    int2* pairs = (int2*)carve((size_t)nnz * 8);
    int* cnt  = (int*)carve((size_t)N_ITEMS * 4);

    float* acc = (float*)d_out;  // [N_TOTAL, D]

    const int B = 256;

    // CSR build + input fp16 conversion
    hipMemsetAsync(cnt, 0, (size_t)N_ITEMS * 4, stream);
    rowptr_u_kernel<<<(N_USERS + 1 + B - 1) / B, B, 0, stream>>>(u_idx, pu, nnz);
    count_i_kernel<<<(nnz + B - 1) / B, B, 0, stream>>>(i_idx, cnt, nnz);
    tohalf_kernel<<<((N_ITEMS * D / 8) + B - 1) / B, B, 0, stream>>>(user_linear, ulH, N_ITEMS * D / 8);
    tohalf_kernel<<<((N_USERS * D / 8) + B - 1) / B, B, 0, stream>>>(item_linear, ilH, N_USERS * D / 8);
    scan_i_kernel<<<1, 1024, 0, stream>>>(cnt, pi, N_ITEMS);
    hipMemsetAsync(cnt, 0, (size_t)N_ITEMS * 4, stream);
    fill_pairs_kernel<<<2048, B, 0, stream>>>(i_idx, u_idx, pi, cnt, pairs, nnz);

    // embeddings (+acc init, +invnorm)
    int rowWaveThreads = N_TOTAL * 64;
    emb_kernel<<<(rowWaveThreads + B - 1) / B, B, 0, stream>>>(ulH, ilH, i_idx, pairs,
                                                              pu, pi, embA, acc, invn);

    // sims (wave per user; writes user diag) then fused w2-gather + item diag
    long long simThreads = (long long)N_USERS * 64;
    sims_kernel<<<(int)((simThreads + B - 1) / B), B, 0, stream>>>(embA, invn, i_idx, pu, sims, diag);
    long long diThreads = (long long)N_ITEMS * 64;
    diagw_kernel<<<(int)((diThreads + B - 1) / B), B, 0, stream>>>(sims, pairs, pi, w2, diag);

    // 3 propagation layers; final one folds the mean (x0.25)
    prop_kernel<false><<<(rowWaveThreads + B - 1) / B, B, 0, stream>>>(embA, embB, acc, sims, w2, diag,
                                                                      i_idx, pairs, pu, pi);
    prop_kernel<false><<<(rowWaveThreads + B - 1) / B, B, 0, stream>>>(embB, embA, acc, sims, w2, diag,
                                                                      i_idx, pairs, pu, pi);
    prop_kernel<true><<<(rowWaveThreads + B - 1) / B, B, 0, stream>>>(embA, embB, acc, sims, w2, diag,
                                                                     i_idx, pairs, pu, pi);
}

// Round 8
// 269.332 us; speedup vs baseline: 1.2232x; 1.2232x over previous
//
#include <hip/hip_runtime.h>
#include <hip/hip_fp16.h>

#define N_USERS 40000
#define N_ITEMS 20000
#define N_TOTAL (N_USERS + N_ITEMS)
#define D 64
#define G_BKT ((N_ITEMS + 63) >> 6)   // 313 buckets of 64 items
#define PAD 16                         // one counter per 64B line

union H8 { uint4 u; __half h[8]; };

// ---------------- CSR construction ----------------

__global__ void rowptr_u_kernel(const int* __restrict__ u_idx, int* __restrict__ pu, int nnz) {
    int u = blockIdx.x * blockDim.x + threadIdx.x;
    if (u > N_USERS) return;
    int lo = 0, hi = nnz;
    while (lo < hi) { int mid = (lo + hi) >> 1; if (u_idx[mid] < u) lo = mid + 1; else hi = mid; }
    pu[u] = lo;
}

// bucket histogram: LDS-aggregated, flushed to line-padded global counters
__global__ void bcount_kernel(const int* __restrict__ i_idx, int* __restrict__ bcnt, int nnz) {
    __shared__ int lc[G_BKT];
    for (int t = threadIdx.x; t < G_BKT; t += blockDim.x) lc[t] = 0;
    __syncthreads();
    int stride = gridDim.x * blockDim.x;
    for (int e = blockIdx.x * blockDim.x + threadIdx.x; e < nnz; e += stride)
        atomicAdd(&lc[__builtin_nontemporal_load(i_idx + e) >> 6], 1);
    __syncthreads();
    for (int t = threadIdx.x; t < G_BKT; t += blockDim.x)
        if (lc[t]) atomicAdd(bcnt + t * PAD, lc[t]);
}

// serial scan over 313 buckets -> bases + cursors; also pi[N_ITEMS] = nnz
__global__ void bscan_kernel(const int* __restrict__ bcnt, int* __restrict__ bbase,
                             int* __restrict__ bcur, int* __restrict__ pi, int nnz) {
    if (threadIdx.x == 0 && blockIdx.x == 0) {
        int run = 0;
        for (int g = 0; g < G_BKT; ++g) {
            bbase[g * PAD] = run;
            bcur[g * PAD] = run;
            run += bcnt[g * PAD];
        }
        bbase[G_BKT * PAD] = run;   // == nnz
        pi[N_ITEMS] = run;
    }
}

// phase 1: scatter (e, (i<<16)|u) into bucket-contiguous staging.
// LDS rank per bucket; ONE padded global atomicAdd per bucket per block.
__global__ void p1_kernel(const int* __restrict__ i_idx, const int* __restrict__ u_idx,
                          int* __restrict__ bcur, int2* __restrict__ tmp, int nnz) {
    const int E = 8;
    __shared__ int lc[G_BKT];
    __shared__ int gb[G_BKT];
    for (int t = threadIdx.x; t < G_BKT; t += blockDim.x) lc[t] = 0;
    __syncthreads();
    int base_e = blockIdx.x * blockDim.x * E;
    int myb[E], myr[E]; int2 myv[E];
    #pragma unroll
    for (int j = 0; j < E; ++j) {
        int e = base_e + j * blockDim.x + threadIdx.x;  // coalesced
        myb[j] = -1;
        if (e < nnz) {
            int i = __builtin_nontemporal_load(i_idx + e);
            int u = __builtin_nontemporal_load(u_idx + e);
            int b = i >> 6;
            myb[j] = b;
            myr[j] = atomicAdd(&lc[b], 1);
            myv[j] = make_int2(e, (i << 16) | u);
        }
    }
    __syncthreads();
    for (int t = threadIdx.x; t < G_BKT; t += blockDim.x)
        gb[t] = lc[t] ? atomicAdd(bcur + t * PAD, lc[t]) : 0;
    __syncthreads();
    #pragma unroll
    for (int j = 0; j < E; ++j)
        if (myb[j] >= 0) tmp[gb[myb[j]] + myr[j]] = myv[j];
}

// phase 2: one block per bucket; block exclusively owns its destination region.
// Two passes over staged region (L2/LLC-hot): histogram -> scan (writes pi) -> place.
__global__ void p2_kernel(const int2* __restrict__ tmp, const int* __restrict__ bbase,
                          int* __restrict__ pi, int2* __restrict__ pairs) {
    __shared__ int hist[64];
    __shared__ int cur[64];
    int g = blockIdx.x;
    int t = threadIdx.x;
    if (t < 64) { hist[t] = 0; cur[t] = 0; }
    __syncthreads();
    int base = bbase[g * PAD], end = bbase[(g + 1) * PAD];
    int lo_item = g << 6;
    for (int k = base + t; k < end; k += blockDim.x)
        atomicAdd(&hist[(tmp[k].y >> 16) & 63], 1);
    __syncthreads();
    if (t == 0) {
        int run = base;
        for (int x = 0; x < 64; ++x) {
            int c = hist[x];
            hist[x] = run;
            if (lo_item + x < N_ITEMS) pi[lo_item + x] = run;
            run += c;
        }
    }
    __syncthreads();
    for (int k = base + t; k < end; k += blockDim.x) {
        int2 v = tmp[k];
        int li = (v.y >> 16) & 63;
        int pos = atomicAdd(&cur[li], 1);
        pairs[hist[li] + pos] = make_int2(v.x, v.y & 0xFFFF);
    }
}

// fused w2-gather + item diag: wave per item
__global__ void diagw_kernel(const float* __restrict__ sims, const int2* __restrict__ pairs,
                             const int* __restrict__ pi, float* __restrict__ w2,
                             float* __restrict__ diag) {
    int i = (blockIdx.x * blockDim.x + threadIdx.x) >> 6;
    int lane = threadIdx.x & 63;
    if (i >= N_ITEMS) return;
    int b = pi[i], e = pi[i + 1];
    float s = 0.f;
    for (int k = b + lane; k < e; k += 64) {
        float w = sims[pairs[k].x];
        w2[k] = w;
        s += w;
    }
    #pragma unroll
    for (int m = 1; m < 64; m <<= 1) s += __shfl_xor(s, m, 64);
    if (lane == 0) diag[N_USERS + i] = s;
}

// fp32 -> fp16, 8 elements per thread
__global__ void tohalf_kernel(const float* __restrict__ src, __half* __restrict__ dst, int n8) {
    int t = blockIdx.x * blockDim.x + threadIdx.x;
    if (t >= n8) return;
    const float4* s = (const float4*)(src + (size_t)t * 8);
    float4 a = s[0], b = s[1];
    H8 o;
    o.h[0] = __float2half(a.x); o.h[1] = __float2half(a.y);
    o.h[2] = __float2half(a.z); o.h[3] = __float2half(a.w);
    o.h[4] = __float2half(b.x); o.h[5] = __float2half(b.y);
    o.h[6] = __float2half(b.z); o.h[7] = __float2half(b.w);
    ((uint4*)dst)[t] = o.u;
}

// ---------------- embeddings (fused: emb + acc init + invnorm; fp16 gather) ----------------
// wave per row; 8 edge-groups x 8 lanes x 8 halves; 2-way unrolled
// cs = column stride in ints (1 for i_idx, 2 for pairs.y)
__global__ void emb_kernel(const __half* __restrict__ ulH, const __half* __restrict__ ilH,
                           const int* __restrict__ i_idx, const int2* __restrict__ pairs,
                           const int* __restrict__ pu, const int* __restrict__ pi,
                           __half* __restrict__ embH, float* __restrict__ acc,
                           float* __restrict__ invn) {
    int wid = (blockIdx.x * blockDim.x + threadIdx.x) >> 6;
    int lane = threadIdx.x & 63;
    if (wid >= N_TOTAL) return;
    int g = lane >> 3, c = lane & 7;
    float s[8];
    #pragma unroll
    for (int j = 0; j < 8; ++j) s[j] = 0.f;
    const __half* tbl; const int* cols; int cs, b, e;
    if (wid < N_USERS) { tbl = ulH; cols = i_idx; cs = 1; b = pu[wid]; e = pu[wid + 1]; }
    else { int i = wid - N_USERS; tbl = ilH; cols = &pairs[0].y; cs = 2; b = pi[i]; e = pi[i + 1]; }
    int k = b + g;
    for (; k + 8 < e; k += 16) {
        H8 r0, r1;
        r0.u = ((const uint4*)(tbl + (size_t)cols[(size_t)k * cs] * D))[c];
        r1.u = ((const uint4*)(tbl + (size_t)cols[(size_t)(k + 8) * cs] * D))[c];
        #pragma unroll
        for (int j = 0; j < 8; ++j) s[j] += __half2float(r0.h[j]) + __half2float(r1.h[j]);
    }
    if (k < e) {
        H8 r0;
        r0.u = ((const uint4*)(tbl + (size_t)cols[(size_t)k * cs] * D))[c];
        #pragma unroll
        for (int j = 0; j < 8; ++j) s[j] += __half2float(r0.h[j]);
    }
    #pragma unroll
    for (int m = 8; m < 64; m <<= 1) {
        #pragma unroll
        for (int j = 0; j < 8; ++j) s[j] += __shfl_xor(s[j], m, 64);
    }
    float nsq = 0.f;
    #pragma unroll
    for (int j = 0; j < 8; ++j) nsq += s[j] * s[j];
    #pragma unroll
    for (int m = 1; m < 8; m <<= 1) nsq += __shfl_xor(nsq, m, 64);
    if (g == 0) {
        H8 o;
        #pragma unroll
        for (int j = 0; j < 8; ++j) o.h[j] = __float2half(s[j]);
        ((uint4*)(embH + (size_t)wid * D))[c] = o.u;
        float4* ap = (float4*)(acc + (size_t)wid * D);
        ap[c * 2]     = make_float4(s[0], s[1], s[2], s[3]);
        ap[c * 2 + 1] = make_float4(s[4], s[5], s[6], s[7]);
        if (c == 0) invn[wid] = 1.f / fmaxf(sqrtf(nsq), 1e-8f);
    }
}

// ---------------- sims (wave per user; fused user diag; fp16 gather; no atomics) ----------------
__global__ void sims_kernel(const __half* __restrict__ embH, const float* __restrict__ invn,
                            const int* __restrict__ i_idx, const int* __restrict__ pu,
                            float* __restrict__ sims, float* __restrict__ diag) {
    int u = (blockIdx.x * blockDim.x + threadIdx.x) >> 6;
    int lane = threadIdx.x & 63;
    if (u >= N_USERS) return;
    int g = lane >> 3, c = lane & 7;
    float invu = invn[u];
    H8 ur; ur.u = ((const uint4*)(embH + (size_t)u * D))[c];
    float un[8];
    #pragma unroll
    for (int j = 0; j < 8; ++j) un[j] = __half2float(ur.h[j]) * invu;
    int b = pu[u], e = pu[u + 1];
    float dsum = 0.f;
    int k = b + g;
    for (; k + 8 < e; k += 16) {
        int i0 = i_idx[k], i1 = i_idx[k + 8];
        H8 r0, r1;
        r0.u = ((const uint4*)(embH + (size_t)(N_USERS + i0) * D))[c];
        r1.u = ((const uint4*)(embH + (size_t)(N_USERS + i1) * D))[c];
        float d0 = 0.f, d1 = 0.f;
        #pragma unroll
        for (int j = 0; j < 8; ++j) {
            d0 += un[j] * __half2float(r0.h[j]);
            d1 += un[j] * __half2float(r1.h[j]);
        }
        #pragma unroll
        for (int m = 1; m < 8; m <<= 1) { d0 += __shfl_xor(d0, m, 64); d1 += __shfl_xor(d1, m, 64); }
        if (c == 0) {
            float sv0 = (d0 * invn[N_USERS + i0] + 1.f) * 0.5f;
            float sv1 = (d1 * invn[N_USERS + i1] + 1.f) * 0.5f;
            sims[k] = sv0; sims[k + 8] = sv1;
            dsum += sv0 + sv1;
        }
    }
    if (k < e) {
        int i0 = i_idx[k];
        H8 r0;
        r0.u = ((const uint4*)(embH + (size_t)(N_USERS + i0) * D))[c];
        float d0 = 0.f;
        #pragma unroll
        for (int j = 0; j < 8; ++j) d0 += un[j] * __half2float(r0.h[j]);
        #pragma unroll
        for (int m = 1; m < 8; m <<= 1) d0 += __shfl_xor(d0, m, 64);
        if (c == 0) {
            float sv0 = (d0 * invn[N_USERS + i0] + 1.f) * 0.5f;
            sims[k] = sv0;
            dsum += sv0;
        }
    }
    #pragma unroll
    for (int m = 8; m < 64; m <<= 1) dsum += __shfl_xor(dsum, m, 64);
    if (lane == 0) diag[u] = dsum;
}

// ---------------- propagation (fp16 gather, fp32 accumulate) ----------------
template <bool FINAL>
__global__ void prop_kernel(const __half* __restrict__ curH, __half* __restrict__ nextH,
                            float* __restrict__ acc, const float* __restrict__ sims,
                            const float* __restrict__ w2, const float* __restrict__ diag,
                            const int* __restrict__ i_idx, const int2* __restrict__ pairs,
                            const int* __restrict__ pu, const int* __restrict__ pi) {
    int wid = (blockIdx.x * blockDim.x + threadIdx.x) >> 6;
    int lane = threadIdx.x & 63;
    if (wid >= N_TOTAL) return;
    int g = lane >> 3, c = lane & 7;
    float s[8];
    #pragma unroll
    for (int j = 0; j < 8; ++j) s[j] = 0.f;
    const int* cols; const float* ws; int cs, b, e, colOff;
    if (wid < N_USERS) { b = pu[wid]; e = pu[wid + 1]; cols = i_idx; cs = 1; ws = sims; colOff = N_USERS; }
    else { int i = wid - N_USERS; b = pi[i]; e = pi[i + 1]; cols = &pairs[0].y; cs = 2; ws = w2; colOff = 0; }
    int k = b + g;
    for (; k + 8 < e; k += 16) {
        float w0 = ws[k], w1 = ws[k + 8];
        H8 r0, r1;
        r0.u = ((const uint4*)(curH + (size_t)(cols[(size_t)k * cs] + colOff) * D))[c];
        r1.u = ((const uint4*)(curH + (size_t)(cols[(size_t)(k + 8) * cs] + colOff) * D))[c];
        #pragma unroll
        for (int j = 0; j < 8; ++j) s[j] += w0 * __half2float(r0.h[j]) + w1 * __half2float(r1.h[j]);
    }
    if (k < e) {
        float w0 = ws[k];
        H8 r0;
        r0.u = ((const uint4*)(curH + (size_t)(cols[(size_t)k * cs] + colOff) * D))[c];
        #pragma unroll
        for (int j = 0; j < 8; ++j) s[j] += w0 * __half2float(r0.h[j]);
    }
    #pragma unroll
    for (int m = 8; m < 64; m <<= 1) {
        #pragma unroll
        for (int j = 0; j < 8; ++j) s[j] += __shfl_xor(s[j], m, 64);
    }
    if (g == 0) {
        float invd = 1.f / (diag[wid] + 1e-7f);
        float v[8];
        #pragma unroll
        for (int j = 0; j < 8; ++j) v[j] = s[j] * invd;
        float4* ap = (float4*)(acc + (size_t)wid * D);
        float4 a0 = ap[c * 2], a1 = ap[c * 2 + 1];
        if (FINAL) {
            a0.x = (a0.x + v[0]) * 0.25f; a0.y = (a0.y + v[1]) * 0.25f;
            a0.z = (a0.z + v[2]) * 0.25f; a0.w = (a0.w + v[3]) * 0.25f;
            a1.x = (a1.x + v[4]) * 0.25f; a1.y = (a1.y + v[5]) * 0.25f;
            a1.z = (a1.z + v[6]) * 0.25f; a1.w = (a1.w + v[7]) * 0.25f;
        } else {
            H8 o;
            #pragma unroll
            for (int j = 0; j < 8; ++j) o.h[j] = __float2half(v[j]);
            ((uint4*)(nextH + (size_t)wid * D))[c] = o.u;
            a0.x += v[0]; a0.y += v[1]; a0.z += v[2]; a0.w += v[3];
            a1.x += v[4]; a1.y += v[5]; a1.z += v[6]; a1.w += v[7];
        }
        ap[c * 2] = a0; ap[c * 2 + 1] = a1;
    }
}

// ---------------- launch ----------------

extern "C" void kernel_launch(void* const* d_in, const int* in_sizes, int n_in,
                              void* d_out, int out_size, void* d_ws, size_t ws_size,
                              hipStream_t stream) {
    const float* user_linear = (const float*)d_in[0];
    const float* item_linear = (const float*)d_in[1];
    const int* u_idx = (const int*)d_in[2];
    const int* i_idx = (const int*)d_in[3];
    const int nnz = in_sizes[2];

    // carve workspace (256B aligned)
    char* p = (char*)d_ws;
    auto carve = [&](size_t bytes) { void* r = (void*)p; p += (bytes + 255) & ~(size_t)255; return r; };
    __half* embA = (__half*)carve((size_t)N_TOTAL * D * 2);
    __half* embB = (__half*)carve((size_t)N_TOTAL * D * 2);
    __half* ulH  = (__half*)carve((size_t)N_ITEMS * D * 2);
    __half* ilH  = (__half*)carve((size_t)N_USERS * D * 2);
    float* sims = (float*)carve((size_t)nnz * 4);
    float* w2   = (float*)carve((size_t)nnz * 4);
    float* diag = (float*)carve((size_t)N_TOTAL * 4);
    float* invn = (float*)carve((size_t)N_TOTAL * 4);
    int* pu   = (int*)carve((size_t)(N_USERS + 1) * 4);
    int* pi   = (int*)carve((size_t)(N_ITEMS + 1) * 4);
    int2* pairs = (int2*)carve((size_t)nnz * 8);
    int* bcnt  = (int*)carve((size_t)(G_BKT + 1) * PAD * 4);
    int* bbase = (int*)carve((size_t)(G_BKT + 1) * PAD * 4);
    int* bcur  = (int*)carve((size_t)(G_BKT + 1) * PAD * 4);

    // staging aliases embA+embB (15.36MB >= 8MB); both dead until emb_kernel
    int2* tmp = (int2*)embA;

    float* acc = (float*)d_out;  // [N_TOTAL, D]

    const int B = 256;

    // CSR build (2-phase bucketed transpose) + input fp16 conversion
    hipMemsetAsync(bcnt, 0, (size_t)(G_BKT + 1) * PAD * 4, stream);
    rowptr_u_kernel<<<(N_USERS + 1 + B - 1) / B, B, 0, stream>>>(u_idx, pu, nnz);
    tohalf_kernel<<<((N_ITEMS * D / 8) + B - 1) / B, B, 0, stream>>>(user_linear, ulH, N_ITEMS * D / 8);
    tohalf_kernel<<<((N_USERS * D / 8) + B - 1) / B, B, 0, stream>>>(item_linear, ilH, N_USERS * D / 8);
    bcount_kernel<<<256, B, 0, stream>>>(i_idx, bcnt, nnz);
    bscan_kernel<<<1, 64, 0, stream>>>(bcnt, bbase, bcur, pi, nnz);
    p1_kernel<<<(nnz + B * 8 - 1) / (B * 8), B, 0, stream>>>(i_idx, u_idx, bcur, tmp, nnz);
    p2_kernel<<<G_BKT, B, 0, stream>>>(tmp, bbase, pi, pairs);

    // embeddings (+acc init, +invnorm)  [overwrites tmp region — tmp dead now]
    int rowWaveThreads = N_TOTAL * 64;
    emb_kernel<<<(rowWaveThreads + B - 1) / B, B, 0, stream>>>(ulH, ilH, i_idx, pairs,
                                                              pu, pi, embA, acc, invn);

    // sims (wave per user; writes user diag) then fused w2-gather + item diag
    long long simThreads = (long long)N_USERS * 64;
    sims_kernel<<<(int)((simThreads + B - 1) / B), B, 0, stream>>>(embA, invn, i_idx, pu, sims, diag);
    long long diThreads = (long long)N_ITEMS * 64;
    diagw_kernel<<<(int)((diThreads + B - 1) / B), B, 0, stream>>>(sims, pairs, pi, w2, diag);

    // 3 propagation layers; final one folds the mean (x0.25)
    prop_kernel<false><<<(rowWaveThreads + B - 1) / B, B, 0, stream>>>(embA, embB, acc, sims, w2, diag,
                                                                      i_idx, pairs, pu, pi);
    prop_kernel<false><<<(rowWaveThreads + B - 1) / B, B, 0, stream>>>(embB, embA, acc, sims, w2, diag,
                                                                      i_idx, pairs, pu, pi);
    prop_kernel<true><<<(rowWaveThreads + B - 1) / B, B, 0, stream>>>(embA, embB, acc, sims, w2, diag,
                                                                     i_idx, pairs, pu, pi);
}

// Round 9
// 266.736 us; speedup vs baseline: 1.2351x; 1.0097x over previous
//
#include <hip/hip_runtime.h>
#include <hip/hip_fp16.h>

#define N_USERS 40000
#define N_ITEMS 20000
#define N_TOTAL (N_USERS + N_ITEMS)
#define D 64
#define G_BKT ((N_ITEMS + 63) >> 6)   // 313 buckets of 64 items
#define PAD 16                         // one counter per 64B line

union H8 { uint4 u; __half h[8]; };

// ---------------- CSR construction ----------------

__global__ void rowptr_u_kernel(const int* __restrict__ u_idx, int* __restrict__ pu, int nnz) {
    int u = blockIdx.x * blockDim.x + threadIdx.x;
    if (u > N_USERS) return;
    int lo = 0, hi = nnz;
    while (lo < hi) { int mid = (lo + hi) >> 1; if (u_idx[mid] < u) lo = mid + 1; else hi = mid; }
    pu[u] = lo;
}

// bucket histogram: LDS-aggregated, flushed to line-padded global counters
__global__ void bcount_kernel(const int* __restrict__ i_idx, int* __restrict__ bcnt, int nnz) {
    __shared__ int lc[G_BKT];
    for (int t = threadIdx.x; t < G_BKT; t += blockDim.x) lc[t] = 0;
    __syncthreads();
    int stride = gridDim.x * blockDim.x;
    for (int e = blockIdx.x * blockDim.x + threadIdx.x; e < nnz; e += stride)
        atomicAdd(&lc[__builtin_nontemporal_load(i_idx + e) >> 6], 1);
    __syncthreads();
    for (int t = threadIdx.x; t < G_BKT; t += blockDim.x)
        if (lc[t]) atomicAdd(bcnt + t * PAD, lc[t]);
}

// serial scan over 313 buckets -> bases + cursors; also pi[N_ITEMS] = nnz
__global__ void bscan_kernel(const int* __restrict__ bcnt, int* __restrict__ bbase,
                             int* __restrict__ bcur, int* __restrict__ pi, int nnz) {
    if (threadIdx.x == 0 && blockIdx.x == 0) {
        int run = 0;
        for (int g = 0; g < G_BKT; ++g) {
            bbase[g * PAD] = run;
            bcur[g * PAD] = run;
            run += bcnt[g * PAD];
        }
        bbase[G_BKT * PAD] = run;   // == nnz
        pi[N_ITEMS] = run;
    }
}

// phase 1: scatter (e, (i<<16)|u) into bucket-contiguous staging.
// LDS rank per bucket; ONE padded global atomicAdd per bucket per block.
__global__ void p1_kernel(const int* __restrict__ i_idx, const int* __restrict__ u_idx,
                          int* __restrict__ bcur, int2* __restrict__ tmp, int nnz) {
    const int E = 8;
    __shared__ int lc[G_BKT];
    __shared__ int gb[G_BKT];
    for (int t = threadIdx.x; t < G_BKT; t += blockDim.x) lc[t] = 0;
    __syncthreads();
    int base_e = blockIdx.x * blockDim.x * E;
    int myb[E], myr[E]; int2 myv[E];
    #pragma unroll
    for (int j = 0; j < E; ++j) {
        int e = base_e + j * blockDim.x + threadIdx.x;  // coalesced
        myb[j] = -1;
        if (e < nnz) {
            int i = __builtin_nontemporal_load(i_idx + e);
            int u = __builtin_nontemporal_load(u_idx + e);
            int b = i >> 6;
            myb[j] = b;
            myr[j] = atomicAdd(&lc[b], 1);
            myv[j] = make_int2(e, (i << 16) | u);
        }
    }
    __syncthreads();
    for (int t = threadIdx.x; t < G_BKT; t += blockDim.x)
        gb[t] = lc[t] ? atomicAdd(bcur + t * PAD, lc[t]) : 0;
    __syncthreads();
    #pragma unroll
    for (int j = 0; j < E; ++j)
        if (myb[j] >= 0) tmp[gb[myb[j]] + myr[j]] = myv[j];
}

// phase 2: one block per bucket; block exclusively owns its destination region.
__global__ void p2_kernel(const int2* __restrict__ tmp, const int* __restrict__ bbase,
                          int* __restrict__ pi, int2* __restrict__ pairs) {
    __shared__ int hist[64];
    __shared__ int cur[64];
    int g = blockIdx.x;
    int t = threadIdx.x;
    if (t < 64) { hist[t] = 0; cur[t] = 0; }
    __syncthreads();
    int base = bbase[g * PAD], end = bbase[(g + 1) * PAD];
    int lo_item = g << 6;
    for (int k = base + t; k < end; k += blockDim.x)
        atomicAdd(&hist[(tmp[k].y >> 16) & 63], 1);
    __syncthreads();
    if (t == 0) {
        int run = base;
        for (int x = 0; x < 64; ++x) {
            int c = hist[x];
            hist[x] = run;
            if (lo_item + x < N_ITEMS) pi[lo_item + x] = run;
            run += c;
        }
    }
    __syncthreads();
    for (int k = base + t; k < end; k += blockDim.x) {
        int2 v = tmp[k];
        int li = (v.y >> 16) & 63;
        int pos = atomicAdd(&cur[li], 1);
        pairs[hist[li] + pos] = make_int2(v.x, v.y & 0xFFFF);
    }
}

// fused w2-gather + item diag: wave per item
__global__ void diagw_kernel(const float* __restrict__ sims, const int2* __restrict__ pairs,
                             const int* __restrict__ pi, float* __restrict__ w2,
                             float* __restrict__ diag) {
    int i = (blockIdx.x * blockDim.x + threadIdx.x) >> 6;
    int lane = threadIdx.x & 63;
    if (i >= N_ITEMS) return;
    int b = pi[i], e = pi[i + 1];
    float s = 0.f;
    for (int k = b + lane; k < e; k += 64) {
        float w = sims[pairs[k].x];
        w2[k] = w;
        s += w;
    }
    #pragma unroll
    for (int m = 1; m < 64; m <<= 1) s += __shfl_xor(s, m, 64);
    if (lane == 0) diag[N_USERS + i] = s;
}

// fp32 -> fp16, 8 elements per thread
__global__ void tohalf_kernel(const float* __restrict__ src, __half* __restrict__ dst, int n8) {
    int t = blockIdx.x * blockDim.x + threadIdx.x;
    if (t >= n8) return;
    const float4* s = (const float4*)(src + (size_t)t * 8);
    float4 a = s[0], b = s[1];
    H8 o;
    o.h[0] = __float2half(a.x); o.h[1] = __float2half(a.y);
    o.h[2] = __float2half(a.z); o.h[3] = __float2half(a.w);
    o.h[4] = __float2half(b.x); o.h[5] = __float2half(b.y);
    o.h[6] = __float2half(b.z); o.h[7] = __float2half(b.w);
    ((uint4*)dst)[t] = o.u;
}

// ---------------- embeddings (fused: emb + invnorm; fp16 gather) ----------------
// wave per row; 8 edge-groups x 8 lanes x 8 halves; 2-way unrolled
__global__ void emb_kernel(const __half* __restrict__ ulH, const __half* __restrict__ ilH,
                           const int* __restrict__ i_idx, const int2* __restrict__ pairs,
                           const int* __restrict__ pu, const int* __restrict__ pi,
                           __half* __restrict__ embH, float* __restrict__ invn) {
    int wid = (blockIdx.x * blockDim.x + threadIdx.x) >> 6;
    int lane = threadIdx.x & 63;
    if (wid >= N_TOTAL) return;
    int g = lane >> 3, c = lane & 7;
    float s[8];
    #pragma unroll
    for (int j = 0; j < 8; ++j) s[j] = 0.f;
    const __half* tbl; const int* cols; int cs, b, e;
    if (wid < N_USERS) { tbl = ulH; cols = i_idx; cs = 1; b = pu[wid]; e = pu[wid + 1]; }
    else { int i = wid - N_USERS; tbl = ilH; cols = &pairs[0].y; cs = 2; b = pi[i]; e = pi[i + 1]; }
    int k = b + g;
    for (; k + 8 < e; k += 16) {
        H8 r0, r1;
        r0.u = ((const uint4*)(tbl + (size_t)cols[(size_t)k * cs] * D))[c];
        r1.u = ((const uint4*)(tbl + (size_t)cols[(size_t)(k + 8) * cs] * D))[c];
        #pragma unroll
        for (int j = 0; j < 8; ++j) s[j] += __half2float(r0.h[j]) + __half2float(r1.h[j]);
    }
    if (k < e) {
        H8 r0;
        r0.u = ((const uint4*)(tbl + (size_t)cols[(size_t)k * cs] * D))[c];
        #pragma unroll
        for (int j = 0; j < 8; ++j) s[j] += __half2float(r0.h[j]);
    }
    #pragma unroll
    for (int m = 8; m < 64; m <<= 1) {
        #pragma unroll
        for (int j = 0; j < 8; ++j) s[j] += __shfl_xor(s[j], m, 64);
    }
    float nsq = 0.f;
    #pragma unroll
    for (int j = 0; j < 8; ++j) nsq += s[j] * s[j];
    #pragma unroll
    for (int m = 1; m < 8; m <<= 1) nsq += __shfl_xor(nsq, m, 64);
    if (g == 0) {
        H8 o;
        #pragma unroll
        for (int j = 0; j < 8; ++j) o.h[j] = __float2half(s[j]);
        ((uint4*)(embH + (size_t)wid * D))[c] = o.u;
        if (c == 0) invn[wid] = 1.f / fmaxf(sqrtf(nsq), 1e-8f);
    }
}

// ---------------- sims (wave per user; fused user diag; fp16 gather; no atomics) ----------------
__global__ void sims_kernel(const __half* __restrict__ embH, const float* __restrict__ invn,
                            const int* __restrict__ i_idx, const int* __restrict__ pu,
                            float* __restrict__ sims, float* __restrict__ diag) {
    int u = (blockIdx.x * blockDim.x + threadIdx.x) >> 6;
    int lane = threadIdx.x & 63;
    if (u >= N_USERS) return;
    int g = lane >> 3, c = lane & 7;
    float invu = invn[u];
    H8 ur; ur.u = ((const uint4*)(embH + (size_t)u * D))[c];
    float un[8];
    #pragma unroll
    for (int j = 0; j < 8; ++j) un[j] = __half2float(ur.h[j]) * invu;
    int b = pu[u], e = pu[u + 1];
    float dsum = 0.f;
    int k = b + g;
    for (; k + 8 < e; k += 16) {
        int i0 = i_idx[k], i1 = i_idx[k + 8];
        H8 r0, r1;
        r0.u = ((const uint4*)(embH + (size_t)(N_USERS + i0) * D))[c];
        r1.u = ((const uint4*)(embH + (size_t)(N_USERS + i1) * D))[c];
        float d0 = 0.f, d1 = 0.f;
        #pragma unroll
        for (int j = 0; j < 8; ++j) {
            d0 += un[j] * __half2float(r0.h[j]);
            d1 += un[j] * __half2float(r1.h[j]);
        }
        #pragma unroll
        for (int m = 1; m < 8; m <<= 1) { d0 += __shfl_xor(d0, m, 64); d1 += __shfl_xor(d1, m, 64); }
        if (c == 0) {
            float sv0 = (d0 * invn[N_USERS + i0] + 1.f) * 0.5f;
            float sv1 = (d1 * invn[N_USERS + i1] + 1.f) * 0.5f;
            sims[k] = sv0; sims[k + 8] = sv1;
            dsum += sv0 + sv1;
        }
    }
    if (k < e) {
        int i0 = i_idx[k];
        H8 r0;
        r0.u = ((const uint4*)(embH + (size_t)(N_USERS + i0) * D))[c];
        float d0 = 0.f;
        #pragma unroll
        for (int j = 0; j < 8; ++j) d0 += un[j] * __half2float(r0.h[j]);
        #pragma unroll
        for (int m = 1; m < 8; m <<= 1) d0 += __shfl_xor(d0, m, 64);
        if (c == 0) {
            float sv0 = (d0 * invn[N_USERS + i0] + 1.f) * 0.5f;
            sims[k] = sv0;
            dsum += sv0;
        }
    }
    #pragma unroll
    for (int m = 8; m < 64; m <<= 1) dsum += __shfl_xor(dsum, m, 64);
    if (lane == 0) diag[u] = dsum;
}

// ---------------- propagation (fp16 gather, fp32 accumulate) ----------------
// non-final: writes next layer (fp16) only. FINAL: fuses the 4-embedding mean,
// reading own rows of e0,e1,e2 (coalesced) and writing d_out fp32 once.
template <bool FINAL>
__global__ void prop_kernel(const __half* __restrict__ curH, __half* __restrict__ nextH,
                            const float* __restrict__ sims, const float* __restrict__ w2,
                            const float* __restrict__ diag,
                            const int* __restrict__ i_idx, const int2* __restrict__ pairs,
                            const int* __restrict__ pu, const int* __restrict__ pi,
                            const __half* __restrict__ e0, const __half* __restrict__ e1,
                            const __half* __restrict__ e2, float* __restrict__ out) {
    int wid = (blockIdx.x * blockDim.x + threadIdx.x) >> 6;
    int lane = threadIdx.x & 63;
    if (wid >= N_TOTAL) return;
    int g = lane >> 3, c = lane & 7;
    float s[8];
    #pragma unroll
    for (int j = 0; j < 8; ++j) s[j] = 0.f;
    const int* cols; const float* ws; int cs, b, e, colOff;
    if (wid < N_USERS) { b = pu[wid]; e = pu[wid + 1]; cols = i_idx; cs = 1; ws = sims; colOff = N_USERS; }
    else { int i = wid - N_USERS; b = pi[i]; e = pi[i + 1]; cols = &pairs[0].y; cs = 2; ws = w2; colOff = 0; }
    int k = b + g;
    for (; k + 8 < e; k += 16) {
        float w0 = ws[k], w1 = ws[k + 8];
        H8 r0, r1;
        r0.u = ((const uint4*)(curH + (size_t)(cols[(size_t)k * cs] + colOff) * D))[c];
        r1.u = ((const uint4*)(curH + (size_t)(cols[(size_t)(k + 8) * cs] + colOff) * D))[c];
        #pragma unroll
        for (int j = 0; j < 8; ++j) s[j] += w0 * __half2float(r0.h[j]) + w1 * __half2float(r1.h[j]);
    }
    if (k < e) {
        float w0 = ws[k];
        H8 r0;
        r0.u = ((const uint4*)(curH + (size_t)(cols[(size_t)k * cs] + colOff) * D))[c];
        #pragma unroll
        for (int j = 0; j < 8; ++j) s[j] += w0 * __half2float(r0.h[j]);
    }
    #pragma unroll
    for (int m = 8; m < 64; m <<= 1) {
        #pragma unroll
        for (int j = 0; j < 8; ++j) s[j] += __shfl_xor(s[j], m, 64);
    }
    if (g == 0) {
        float invd = 1.f / (diag[wid] + 1e-7f);
        float v[8];
        #pragma unroll
        for (int j = 0; j < 8; ++j) v[j] = s[j] * invd;
        if (FINAL) {
            H8 r0, r1, r2;
            r0.u = ((const uint4*)(e0 + (size_t)wid * D))[c];
            r1.u = ((const uint4*)(e1 + (size_t)wid * D))[c];
            r2.u = ((const uint4*)(e2 + (size_t)wid * D))[c];
            float o[8];
            #pragma unroll
            for (int j = 0; j < 8; ++j)
                o[j] = (v[j] + __half2float(r0.h[j]) + __half2float(r1.h[j]) + __half2float(r2.h[j])) * 0.25f;
            float4* op = (float4*)(out + (size_t)wid * D);
            op[c * 2]     = make_float4(o[0], o[1], o[2], o[3]);
            op[c * 2 + 1] = make_float4(o[4], o[5], o[6], o[7]);
        } else {
            H8 o;
            #pragma unroll
            for (int j = 0; j < 8; ++j) o.h[j] = __float2half(v[j]);
            ((uint4*)(nextH + (size_t)wid * D))[c] = o.u;
        }
    }
}

// ---------------- launch ----------------

extern "C" void kernel_launch(void* const* d_in, const int* in_sizes, int n_in,
                              void* d_out, int out_size, void* d_ws, size_t ws_size,
                              hipStream_t stream) {
    const float* user_linear = (const float*)d_in[0];
    const float* item_linear = (const float*)d_in[1];
    const int* u_idx = (const int*)d_in[2];
    const int* i_idx = (const int*)d_in[3];
    const int nnz = in_sizes[2];

    // carve workspace (256B aligned)
    char* p = (char*)d_ws;
    auto carve = [&](size_t bytes) { void* r = (void*)p; p += (bytes + 255) & ~(size_t)255; return r; };
    __half* embA = (__half*)carve((size_t)N_TOTAL * D * 2);
    __half* embB = (__half*)carve((size_t)N_TOTAL * D * 2);
    __half* embC = (__half*)carve((size_t)N_TOTAL * D * 2);
    __half* ulH  = (__half*)carve((size_t)N_ITEMS * D * 2);
    __half* ilH  = (__half*)carve((size_t)N_USERS * D * 2);
    float* sims = (float*)carve((size_t)nnz * 4);
    float* w2   = (float*)carve((size_t)nnz * 4);
    float* diag = (float*)carve((size_t)N_TOTAL * 4);
    float* invn = (float*)carve((size_t)N_TOTAL * 4);
    int* pu   = (int*)carve((size_t)(N_USERS + 1) * 4);
    int* pi   = (int*)carve((size_t)(N_ITEMS + 1) * 4);
    int2* pairs = (int2*)carve((size_t)nnz * 8);
    int* bcnt  = (int*)carve((size_t)(G_BKT + 1) * PAD * 4);
    int* bbase = (int*)carve((size_t)(G_BKT + 1) * PAD * 4);
    int* bcur  = (int*)carve((size_t)(G_BKT + 1) * PAD * 4);

    // staging aliases embA+embB (15.36MB >= 8MB); both dead until emb_kernel
    int2* tmp = (int2*)embA;

    float* out = (float*)d_out;  // [N_TOTAL, D]

    const int B = 256;

    // CSR build (2-phase bucketed transpose) + input fp16 conversion
    hipMemsetAsync(bcnt, 0, (size_t)(G_BKT + 1) * PAD * 4, stream);
    rowptr_u_kernel<<<(N_USERS + 1 + B - 1) / B, B, 0, stream>>>(u_idx, pu, nnz);
    tohalf_kernel<<<((N_ITEMS * D / 8) + B - 1) / B, B, 0, stream>>>(user_linear, ulH, N_ITEMS * D / 8);
    tohalf_kernel<<<((N_USERS * D / 8) + B - 1) / B, B, 0, stream>>>(item_linear, ilH, N_USERS * D / 8);
    bcount_kernel<<<256, B, 0, stream>>>(i_idx, bcnt, nnz);
    bscan_kernel<<<1, 64, 0, stream>>>(bcnt, bbase, bcur, pi, nnz);
    p1_kernel<<<(nnz + B * 8 - 1) / (B * 8), B, 0, stream>>>(i_idx, u_idx, bcur, tmp, nnz);
    p2_kernel<<<G_BKT, B, 0, stream>>>(tmp, bbase, pi, pairs);

    // embeddings (+invnorm)  [overwrites tmp region — tmp dead now]
    int rowWaveThreads = N_TOTAL * 64;
    emb_kernel<<<(rowWaveThreads + B - 1) / B, B, 0, stream>>>(ulH, ilH, i_idx, pairs,
                                                              pu, pi, embA, invn);

    // sims (wave per user; writes user diag) then fused w2-gather + item diag
    long long simThreads = (long long)N_USERS * 64;
    sims_kernel<<<(int)((simThreads + B - 1) / B), B, 0, stream>>>(embA, invn, i_idx, pu, sims, diag);
    long long diThreads = (long long)N_ITEMS * 64;
    diagw_kernel<<<(int)((diThreads + B - 1) / B), B, 0, stream>>>(sims, pairs, pi, w2, diag);

    // 3 propagation layers; final one fuses the 4-embedding mean into d_out
    prop_kernel<false><<<(rowWaveThreads + B - 1) / B, B, 0, stream>>>(embA, embB, sims, w2, diag,
                                                                      i_idx, pairs, pu, pi,
                                                                      nullptr, nullptr, nullptr, nullptr);
    prop_kernel<false><<<(rowWaveThreads + B - 1) / B, B, 0, stream>>>(embB, embC, sims, w2, diag,
                                                                      i_idx, pairs, pu, pi,
                                                                      nullptr, nullptr, nullptr, nullptr);
    prop_kernel<true><<<(rowWaveThreads + B - 1) / B, B, 0, stream>>>(embC, nullptr, sims, w2, diag,
                                                                     i_idx, pairs, pu, pi,
                                                                     embA, embB, embC, out);
}